// Round 1
// baseline (539.495 us; speedup 1.0000x reference)
//
#include <hip/hip_runtime.h>
#include <hip/hip_bf16.h>

// Problem constants (from reference): B=512, F=1180, A=50, C=1024, INIT_MID=16
#define B_ 512
#define F_ 1180
#define A_ 50
#define C_ 1024
#define NTA (A_ * C_ * 2)   // 102400 TA rows of F_ floats each

// ---------------------------------------------------------------------------
// Kernel 1: pack the first 64 features of every TA row (include bit: state>16)
// and every x row (bit: x>0.5) into one u64 word per row via wave ballot.
// One wave (64 lanes) per row: lane reads row[lane] -> fully coalesced 256B.
// ---------------------------------------------------------------------------
__global__ __launch_bounds__(256) void pack_word0(
    const float* __restrict__ ta,   // [A,C,2,F]
    const float* __restrict__ x,    // [B,F]
    unsigned long long* __restrict__ taw,  // [NTA]
    unsigned long long* __restrict__ xw)   // [B]
{
    int wave = (int)(blockIdx.x * (blockDim.x >> 6)) + (threadIdx.x >> 6);
    int lane = threadIdx.x & 63;
    if (wave < NTA) {
        float v = ta[(size_t)wave * F_ + lane];
        unsigned long long m = __ballot(v > 16.0f);
        if (lane == 0) taw[wave] = m;
    } else if (wave < NTA + B_) {
        int b = wave - NTA;
        float v = x[(size_t)b * F_ + lane];
        unsigned long long m = __ballot(v > 0.5f);
        if (lane == 0) xw[b] = m;
    }
}

// ---------------------------------------------------------------------------
// Kernel 2: clause voting. Block = (class a, 64-batch chunk), thread = clause.
// Fast path: viol64 = (cp0 & ~xb) | (cn0 & xb) over features 0..63 — a
// necessary condition for the clause to fire. viol64==0 has p ~= 2^-64 on
// this data, so the exact fallback (scan features 64..F from the raw floats)
// essentially never runs, but keeps the kernel correct for arbitrary inputs.
// ---------------------------------------------------------------------------
__global__ __launch_bounds__(1024) void clause_vote(
    const unsigned long long* __restrict__ taw,   // [NTA] = [A*C][2]
    const unsigned long long* __restrict__ xw,    // [B]
    const float* __restrict__ ta,                 // [A,C,2,F] raw (rare path)
    const float* __restrict__ x,                  // [B,F]     raw (rare path)
    const float* __restrict__ sign,               // [A,C]
    const int*   __restrict__ Tptr,               // scalar T (int32 or f32 bits)
    float* __restrict__ out)                      // [B,A]
{
    const int a     = blockIdx.x;          // 0..A-1
    const int bbase = blockIdx.y * 64;     // batch chunk
    const int c     = threadIdx.x;         // 0..C-1

    __shared__ float votes[64];
    if (threadIdx.x < 64) votes[threadIdx.x] = 0.0f;
    __syncthreads();

    // Coalesced 16B/lane: consecutive clauses -> consecutive (pos,neg) pairs.
    const size_t rc = (size_t)(a * C_ + c);
    unsigned long long cp0 = taw[rc * 2 + 0];
    unsigned long long cn0 = taw[rc * 2 + 1];

#pragma unroll 4
    for (int i = 0; i < 64; ++i) {
        // Uniform address (no tid) -> scalar load through the constant cache.
        unsigned long long xb = xw[bbase + i];
        unsigned long long viol = (cp0 & ~xb) | (cn0 & xb);
        if (viol == 0ULL) {
            // ---- exact rare path: verify remaining features from raw data ----
            const int b = bbase + i;
            const float* tp = ta + rc * 2 * (size_t)F_;
            const float* tn = tp + F_;
            const float* xr = x + (size_t)b * F_;
            bool fire = true;
            for (int f = 64; f < F_; ++f) {
                bool xi = xr[f] > 0.5f;
                if ((tp[f] > 16.0f && !xi) || (tn[f] > 16.0f && xi)) {
                    fire = false;
                    break;
                }
            }
            if (fire) atomicAdd(&votes[i], sign[rc]);
        }
    }
    __syncthreads();

    if (threadIdx.x < 64) {
        // Robust T decode: small int bit-pattern => int32 scalar, else float32.
        int iv = Tptr[0];
        float Tf = ((unsigned)iv < 0x10000u) ? (float)iv : __int_as_float(iv);
        float v = votes[threadIdx.x];
        v = fminf(fmaxf(v, -Tf), Tf);
        out[(size_t)(bbase + threadIdx.x) * A_ + a] = v;
    }
}

extern "C" void kernel_launch(void* const* d_in, const int* in_sizes, int n_in,
                              void* d_out, int out_size, void* d_ws, size_t ws_size,
                              hipStream_t stream) {
    const float* x    = (const float*)d_in[0];  // [B,F] binary features
    const float* ta   = (const float*)d_in[1];  // [A,C,2,F] TA states
    const float* sign = (const float*)d_in[2];  // [A,C] clause signs
    const int*   Tp   = (const int*)d_in[3];    // scalar T
    float* out = (float*)d_out;                 // [B,A]

    // Workspace layout: packed word0 per TA row, then per x row. < 1 MB total.
    unsigned long long* taw = (unsigned long long*)d_ws;
    unsigned long long* xw  = taw + NTA;

    // Kernel 1: (NTA + B) waves, 4 waves per 256-thread block. Exact cover.
    {
        int total_waves = NTA + B_;                 // 102912
        int blocks = (total_waves + 3) / 4;         // 25728
        pack_word0<<<blocks, 256, 0, stream>>>(ta, x, taw, xw);
    }

    // Kernel 2: grid (A, B/64), 1024 threads = 1024 clauses.
    {
        dim3 grid(A_, B_ / 64);
        clause_vote<<<grid, 1024, 0, stream>>>(taw, xw, ta, x, sign, Tp, out);
    }
}

// Round 2
// 530.623 us; speedup vs baseline: 1.0167x; 1.0167x over previous
//
#include <hip/hip_runtime.h>
#include <hip/hip_bf16.h>

// Problem constants (from reference): B=512, F=1180, A=50, C=1024, INIT_MID=16
#define B_ 512
#define F_ 1180
#define A_ 50
#define C_ 1024
#define NTA (A_ * C_ * 2)   // 102400 TA rows of F_ floats each

// ---------------------------------------------------------------------------
// Kernel 1: pack the first 64 features of every TA row (include bit: state>16)
// and every x row (bit: x>0.5) into one u64 word per row via wave ballot.
// One wave (64 lanes) per row: lane reads row[lane] -> fully coalesced 256B.
// Total read: (102400+512)*256B ~= 26 MB  ->  ~5 us at HBM ceiling.
// ---------------------------------------------------------------------------
__global__ __launch_bounds__(256) void pack_word0(
    const float* __restrict__ ta,   // [A,C,2,F]
    const float* __restrict__ x,    // [B,F]
    unsigned long long* __restrict__ taw,  // [NTA]
    unsigned long long* __restrict__ xw)   // [B]
{
    int wave = (int)(blockIdx.x * (blockDim.x >> 6)) + (threadIdx.x >> 6);
    int lane = threadIdx.x & 63;
    if (wave < NTA) {
        float v = ta[(size_t)wave * F_ + lane];
        unsigned long long m = __ballot(v > 16.0f);
        if (lane == 0) taw[wave] = m;
    } else if (wave < NTA + B_) {
        int b = wave - NTA;
        float v = x[(size_t)b * F_ + lane];
        unsigned long long m = __ballot(v > 0.5f);
        if (lane == 0) xw[b] = m;
    }
}

// ---------------------------------------------------------------------------
// Kernel 2: clause voting. Block = (class a, 64-batch chunk), thread = clause.
// viol64 = (cp0 & ~xb) | (cn0 & xb) over features 0..63 is a necessary
// condition for the clause to fire; on ~Bernoulli(0.5) data P(viol64==0)
// ~= 2^-64, so the exact fallback (features 64..F from raw floats) almost
// never runs but keeps the kernel correct for arbitrary inputs.
// Hot loop is branch-free: accumulate a 64-bit fire mask, handle survivors
// after the loop.
// ---------------------------------------------------------------------------
__global__ __launch_bounds__(1024) void clause_vote(
    const unsigned long long* __restrict__ taw,   // [NTA] = [A*C][2]
    const unsigned long long* __restrict__ xw,    // [B]
    const float* __restrict__ ta,                 // [A,C,2,F] raw (rare path)
    const float* __restrict__ x,                  // [B,F]     raw (rare path)
    const float* __restrict__ sign,               // [A,C]
    const int*   __restrict__ Tptr,               // scalar T (int32 or f32 bits)
    float* __restrict__ out)                      // [B,A]
{
    const int a     = blockIdx.x;          // 0..A-1
    const int bbase = blockIdx.y * 64;     // batch chunk
    const int c     = threadIdx.x;         // 0..C-1

    __shared__ unsigned long long s_x[64];
    __shared__ float votes[64];
    if (threadIdx.x < 64) {
        s_x[threadIdx.x]   = xw[bbase + threadIdx.x];
        votes[threadIdx.x] = 0.0f;
    }
    __syncthreads();

    // Coalesced 16B/lane: consecutive clauses -> consecutive (pos,neg) pairs.
    const size_t rc = (size_t)(a * C_ + c);
    const unsigned long long cp0 = taw[rc * 2 + 0];
    const unsigned long long cn0 = taw[rc * 2 + 1];

    // Branch-free hot loop: bit i of fire_mask = "clause may fire for batch
    // bbase+i" (all 64 first-feature checks passed).
    unsigned long long fire_mask = 0ULL;
#pragma unroll
    for (int i = 0; i < 64; ++i) {
        unsigned long long viol = (cp0 & ~s_x[i]) | (cn0 & s_x[i]);
        fire_mask |= (viol == 0ULL) ? (1ULL << i) : 0ULL;
    }

    if (fire_mask) {
        // ---- exact rare path: verify remaining features from raw data ----
        const float* tp = ta + rc * 2 * (size_t)F_;
        const float* tn = tp + F_;
        while (fire_mask) {
            int i = __builtin_ctzll(fire_mask);
            fire_mask &= fire_mask - 1;
            const float* xr = x + (size_t)(bbase + i) * F_;
            bool fire = true;
            for (int f = 64; f < F_; ++f) {
                bool xi = xr[f] > 0.5f;
                if ((tp[f] > 16.0f && !xi) || (tn[f] > 16.0f && xi)) {
                    fire = false;
                    break;
                }
            }
            if (fire) atomicAdd(&votes[i], sign[rc]);
        }
    }
    __syncthreads();

    if (threadIdx.x < 64) {
        // Robust T decode: small int bit-pattern => int32 scalar, else float32.
        int iv = Tptr[0];
        float Tf = ((unsigned)iv < 0x10000u) ? (float)iv : __int_as_float(iv);
        float v = votes[threadIdx.x];
        v = fminf(fmaxf(v, -Tf), Tf);
        out[(size_t)(bbase + threadIdx.x) * A_ + a] = v;
    }
}

extern "C" void kernel_launch(void* const* d_in, const int* in_sizes, int n_in,
                              void* d_out, int out_size, void* d_ws, size_t ws_size,
                              hipStream_t stream) {
    const float* x    = (const float*)d_in[0];  // [B,F] binary features
    const float* ta   = (const float*)d_in[1];  // [A,C,2,F] TA states
    const float* sign = (const float*)d_in[2];  // [A,C] clause signs
    const int*   Tp   = (const int*)d_in[3];    // scalar T
    float* out = (float*)d_out;                 // [B,A]

    // Workspace layout: packed word0 per TA row, then per x row. < 1 MB total.
    unsigned long long* taw = (unsigned long long*)d_ws;
    unsigned long long* xw  = taw + NTA;

    // Kernel 1: (NTA + B) waves, 4 waves per 256-thread block. Exact cover.
    {
        int total_waves = NTA + B_;                 // 102912
        int blocks = (total_waves + 3) / 4;         // 25728
        pack_word0<<<blocks, 256, 0, stream>>>(ta, x, taw, xw);
    }

    // Kernel 2: grid (A, B/64), 1024 threads = 1024 clauses.
    {
        dim3 grid(A_, B_ / 64);
        clause_vote<<<grid, 1024, 0, stream>>>(taw, xw, ta, x, sign, Tp, out);
    }
}